// Round 5
// baseline (485.624 us; speedup 1.0000x reference)
//
#include <hip/hip_runtime.h>
#include <math.h>

#define B_ 64
#define P_ 196
#define D_ 768
#define C_ 201
#define K_ 5
#define N_ (B_*P_)      // 12544
#define CK_ (C_*K_)     // 1005
#define NPAD 1024
#define NCLS 200
#define GAMMA_ 0.999f
#define INV_TEMP 5.0f
#define INV_EPS 20.0f
#define CAP2 256
#define EPAD 8          // padded floats per (c,slot) in EList
#define MTILES 98       // 12544/128
#define ROWS_TOT (2*N_ + NPAD)   // 26112 rows for the norm pass
#define NBLK 784        // persistent grid; MUST be <= co-resident capacity (4/CU * 256 = 1024)

typedef short s16x8 __attribute__((ext_vector_type(8)));
typedef float f32x4 __attribute__((ext_vector_type(4)));
typedef unsigned short u16x4 __attribute__((ext_vector_type(4)));

typedef __attribute__((address_space(3))) void lds_void;
typedef __attribute__((address_space(1))) const void g_void;
#define GLD16(gp, lp) __builtin_amdgcn_global_load_lds((g_void*)(gp), (lds_void*)(lp), 16, 0, 0)

__device__ __forceinline__ unsigned short f2bf(float f) {
    unsigned int u = __float_as_uint(f);
    unsigned int r = (u + 0x7FFFu + ((u >> 16) & 1u)) >> 16;
    return (unsigned short)r;
}

// Monotonic-generation grid barrier. bar[0]=arrival count (never reset in-kernel),
// bar[1]=generation. Both zeroed by hipMemsetAsync before every launch, so replay-safe.
// Release/acquire via __threadfence (device scope: buffer_wbl2/inv sc1 -> cross-XCD safe).
__device__ __forceinline__ void gsync(unsigned* bar, unsigned phase) {
    __syncthreads();
    if (threadIdx.x == 0) {
        __threadfence();
        unsigned old = atomicAdd(&bar[0], 1u);
        if (old == (unsigned)NBLK * phase - 1u) {
            atomicExch(&bar[1], phase);
        } else {
            while (atomicAdd(&bar[1], 0u) < phase) __builtin_amdgcn_s_sleep(2);
        }
        __threadfence();
    }
    __syncthreads();
}

// ---------------- single persistent kernel: norm -> gemm -> imgcls/compact -> sinkema ----
// R9: 4 launches -> 1. Eliminates all inter-kernel launch/drain overhead and gives exact
// attribution (this kernel's dur == total GPU time). Co-residency: LDS union = 36864 B
// -> 4 blocks/CU -> 1024 slots >= 784. GEMM phase = R5 2-buffer config (49.9us standalone).
#define BM 128
#define BN 128
#define BKq 32
__global__ __launch_bounds__(256, 4) void mega_kernel(
        const float* __restrict__ patch, const float* __restrict__ rawp,
        const float* __restrict__ proto, const float* __restrict__ saw,
        const int* __restrict__ labels,
        float* __restrict__ logits, float* __restrict__ img, float* __restrict__ cls,
        float* __restrict__ assign, float* __restrict__ pnew,
        unsigned* __restrict__ bar, int* __restrict__ cnt, float* __restrict__ invR,
        unsigned short* __restrict__ Abf, unsigned short* __restrict__ Bbf,
        int* __restrict__ idxList, float* __restrict__ EList, float* __restrict__ part) {
    __shared__ union {
        struct { short As[2][BM * BKq]; short Bs[2][BN * BKq]; float maxw[4][2][BN]; } g; // 36864 B
        struct { float s_w[K_][CAP2]; int s_idx[CAP2]; } s;                               // 6144 B
        struct { float simg[CK_]; } p;                                                    // 4020 B
    } u;
    int bid = blockIdx.x;
    int tid = threadIdx.x;
    int w = tid >> 6;
    int lane = tid & 63;

    // ================= P1: norms + pre-scaled bf16 conversion (grid-strided rows) =========
    for (int gw = bid * 4 + w; gw < ROWS_TOT; gw += NBLK * 4) {
        const float* src; unsigned short* dst; int realR; int r; bool wantInv = false;
        if (gw < N_) { r = gw; src = patch; dst = Abf; realR = N_; }
        else if (gw < 2 * N_) { r = gw - N_; src = rawp; dst = nullptr; realR = N_; wantInv = true; }
        else { r = gw - 2 * N_; src = proto; dst = Bbf; realR = CK_; }
        unsigned short* brow = dst ? dst + (size_t)r * D_ : nullptr;
        if (r >= realR) {  // zero-pad proto rows
            u16x4 z = (u16x4)0;
            *(u16x4*)(brow + lane * 4)       = z;
            *(u16x4*)(brow + lane * 4 + 256) = z;
            *(u16x4*)(brow + lane * 4 + 512) = z;
            continue;
        }
        const float4* row4 = (const float4*)(src + (size_t)r * D_);
        float4 v0 = row4[lane], v1 = row4[lane + 64], v2 = row4[lane + 128];
        float s = v0.x*v0.x + v0.y*v0.y + v0.z*v0.z + v0.w*v0.w
                + v1.x*v1.x + v1.y*v1.y + v1.z*v1.z + v1.w*v1.w
                + v2.x*v2.x + v2.y*v2.y + v2.z*v2.z + v2.w*v2.w;
#pragma unroll
        for (int o = 1; o < 64; o <<= 1) s += __shfl_xor(s, o, 64);
        float sc = 1.f / fmaxf(sqrtf(s), 1e-12f);
        if (brow) {
            u16x4 p0 = { f2bf(v0.x*sc), f2bf(v0.y*sc), f2bf(v0.z*sc), f2bf(v0.w*sc) };
            u16x4 p1 = { f2bf(v1.x*sc), f2bf(v1.y*sc), f2bf(v1.z*sc), f2bf(v1.w*sc) };
            u16x4 p2 = { f2bf(v2.x*sc), f2bf(v2.y*sc), f2bf(v2.z*sc), f2bf(v2.w*sc) };
            *(u16x4*)(brow + lane * 4)       = p0;
            *(u16x4*)(brow + lane * 4 + 256) = p1;
            *(u16x4*)(brow + lane * 4 + 512) = p2;
        } else if (wantInv && lane == 0) invR[r] = sc;
    }
    gsync(bar, 1);

    // ================= P2: bf16 MFMA GEMM + fused per-tile image max ======================
    {
        // XCD-aware chunked swizzle (bijective: 784 = 8*98)
        int swz = (bid & 7) * MTILES + (bid >> 3);
        int mtile = swz >> 3;
        int ntile = swz & 7;
        int mBase = mtile * BM;
        int nBase = ntile * BN;
        int wm = (w >> 1) * 64;
        int wn = (w & 1) * 64;
        int mrow = lane & 15;
        int kq = (lane >> 4) * 8;

        f32x4 acc[4][4];
#pragma unroll
        for (int i = 0; i < 4; ++i)
#pragma unroll
            for (int j = 0; j < 4; ++j) acc[i][j] = (f32x4)(0.f);

        int c0 = tid, c1 = tid + 256;
        const unsigned short* ga0 = Abf + (size_t)(mBase + (c0 >> 2)) * D_ + (c0 & 3) * 8;
        const unsigned short* ga1 = Abf + (size_t)(mBase + (c1 >> 2)) * D_ + (c1 & 3) * 8;
        const unsigned short* gb0 = Bbf + (size_t)(nBase + (c0 >> 2)) * D_ + (c0 & 3) * 8;
        const unsigned short* gb1 = Bbf + (size_t)(nBase + (c1 >> 2)) * D_ + (c1 & 3) * 8;

        auto stage = [&](int buf, int k0) {
            GLD16(ga0 + k0, &u.g.As[buf][c0 * 8]);
            GLD16(ga1 + k0, &u.g.As[buf][c1 * 8]);
            GLD16(gb0 + k0, &u.g.Bs[buf][c0 * 8]);
            GLD16(gb1 + k0, &u.g.Bs[buf][c1 * 8]);
        };

        stage(0, 0);
        __syncthreads();
        int cur = 0;
        for (int k0 = 0; k0 < D_; k0 += BKq) {
            int nk = k0 + BKq;
            if (nk < D_) stage(cur ^ 1, nk);   // prefetch next tile into other buffer
            s16x8 a[4], b[4];
#pragma unroll
            for (int i = 0; i < 4; ++i)
                a[i] = *(const s16x8*)&u.g.As[cur][(wm + 16 * i + mrow) * BKq + kq];
#pragma unroll
            for (int j = 0; j < 4; ++j)
                b[j] = *(const s16x8*)&u.g.Bs[cur][(wn + 16 * j + mrow) * BKq + kq];
#pragma unroll
            for (int i = 0; i < 4; ++i)
#pragma unroll
                for (int j = 0; j < 4; ++j)
                    acc[i][j] = __builtin_amdgcn_mfma_f32_16x16x32_bf16(a[i], b[j], acc[i][j], 0, 0, 0);
            __syncthreads();
            cur ^= 1;
        }

        // epilogue: plain stores (NT stores measured worse: WRITE_SIZE 55->96MB)
#pragma unroll
        for (int i = 0; i < 4; ++i) {
            int gm = mBase + wm + 16 * i + (lane >> 4) * 4;
#pragma unroll
            for (int j = 0; j < 4; ++j) {
                int gn = nBase + wn + 16 * j + (lane & 15);
                if (gn < CK_) {
                    logits[(size_t)(gm + 0) * CK_ + gn] = acc[i][j][0];
                    logits[(size_t)(gm + 1) * CK_ + gn] = acc[i][j][1];
                    logits[(size_t)(gm + 2) * CK_ + gn] = acc[i][j][2];
                    logits[(size_t)(gm + 3) * CK_ + gn] = acc[i][j][3];
                }
            }
        }

        // fused max over this tile's rows, split by image boundary (tile spans <=2 images)
        int imgA = mBase / 196;
        int rstar = 196 * (imgA + 1);
#pragma unroll
        for (int j = 0; j < 4; ++j) {
            float m0 = -INFINITY, m1 = -INFINITY;
#pragma unroll
            for (int i = 0; i < 4; ++i) {
                int gm = mBase + wm + 16 * i + (lane >> 4) * 4;
#pragma unroll
                for (int r = 0; r < 4; ++r) {
                    float v = acc[i][j][r];
                    if (gm + r >= rstar) m1 = fmaxf(m1, v); else m0 = fmaxf(m0, v);
                }
            }
            m0 = fmaxf(m0, __shfl_xor(m0, 16)); m0 = fmaxf(m0, __shfl_xor(m0, 32));
            m1 = fmaxf(m1, __shfl_xor(m1, 16)); m1 = fmaxf(m1, __shfl_xor(m1, 32));
            if (lane < 16) {
                u.g.maxw[w][0][wn + 16 * j + lane] = m0;
                u.g.maxw[w][1][wn + 16 * j + lane] = m1;
            }
        }
        __syncthreads();
        int s = tid >> 7, col = tid & 127, h = col >> 6;
        float vmax = fmaxf(u.g.maxw[h][s][col], u.g.maxw[h + 2][s][col]);
        part[(size_t)(mtile * 2 + s) * 1024 + nBase + col] = vmax;
    }
    gsync(bar, 2);

    // ================= P3: imgcls (blocks 0..63) + compaction (blocks 64..112) ============
    if (bid < B_) {
        int b = bid;
        int t0 = (196 * b) >> 7;
        int t1 = (196 * b + 195) >> 7;
        for (int n = tid; n < CK_; n += 256) {
            float m = -INFINITY;
            for (int t = t0; t <= t1; ++t) {
                int iA = (t << 7) / 196;
                int s = (iA == b) ? 0 : 1;
                m = fmaxf(m, part[(size_t)(t * 2 + s) * 1024 + n]);
            }
            img[b * CK_ + n] = m;
            u.p.simg[n] = m;
        }
        __syncthreads();
        int c = tid;
        if (c < NCLS) {
            float wv[K_];
            float mx = -INFINITY;
#pragma unroll
            for (int k = 0; k < K_; ++k) { wv[k] = saw[c * K_ + k]; mx = fmaxf(mx, wv[k]); }
            float ssum = 0.f;
#pragma unroll
            for (int k = 0; k < K_; ++k) { wv[k] = expf(wv[k] - mx); ssum += wv[k]; }
            float a = 0.f;
#pragma unroll
            for (int k = 0; k < K_; ++k)
                a += u.p.simg[c * K_ + k] * (wv[k] / ssum * (float)K_);
            cls[b * NCLS + c] = a * INV_TEMP;
        }
    } else {
        int n = (bid - B_) * 256 + tid;
        if (n < N_) {
            int c = labels[n];
            int slot = atomicAdd(&cnt[c], 1);
            if (slot < CAP2) {
                idxList[c * CAP2 + slot] = n;
                const float* lp = logits + (size_t)n * CK_ + c * K_;
                float e0 = expf(lp[0] * INV_EPS), e1 = expf(lp[1] * INV_EPS);
                float e2 = expf(lp[2] * INV_EPS), e3 = expf(lp[3] * INV_EPS);
                float e4 = expf(lp[4] * INV_EPS);
                float* ep = EList + ((size_t)c * CAP2 + slot) * EPAD;
                float4 v4 = { e0, e1, e2, e3 };
                *(float4*)ep = v4;
                ep[4] = e4;
            }
        }
    }
    gsync(bar, 3);

    // ================= P4: sinkhorn + EMA, one block per class (blocks 0..200) ============
    if (bid < C_) {
        int c = bid;
        int Nc = cnt[c]; if (Nc > CAP2) Nc = CAP2;
        size_t protoOff = (size_t)c * K_ * D_;
        if (Nc == 0) {  // absent class: copy prototypes through
            for (int i = tid; i < K_ * D_; i += 256)
                pnew[protoOff + i] = proto[protoOff + i];
            return;
        }
        for (int i = tid; i < CAP2; i += 256)
            u.s.s_idx[i] = (i < Nc) ? idxList[c * CAP2 + i] : 0;

        if (tid < 64) {   // wave 0: sinkhorn (reads idxList directly: no s_idx race)
            int ln = tid;
            float e[CAP2/64][K_];
            float cn[CAP2/64];
#pragma unroll
            for (int j = 0; j < CAP2/64; ++j) {
                int n = j * 64 + ln;
                bool v = n < Nc;
                cn[j] = v ? 1.f : 0.f;
                const float* ep = EList + ((size_t)c * CAP2 + n) * EPAD;
                float4 v4 = v ? *(const float4*)ep : make_float4(0.f, 0.f, 0.f, 0.f);
                e[j][0] = v4.x; e[j][1] = v4.y; e[j][2] = v4.z; e[j][3] = v4.w;
                e[j][4] = v ? ep[4] : 0.f;
            }
            float r[K_];
            for (int it = 0; it < 3; ++it) {
#pragma unroll
                for (int k = 0; k < K_; ++k) {
                    float s = 0.f;
#pragma unroll
                    for (int j = 0; j < CAP2/64; ++j) s += e[j][k] * cn[j];
                    for (int o = 32; o > 0; o >>= 1) s += __shfl_xor(s, o, 64);
                    r[k] = 1.f / ((float)K_ * s);
                }
#pragma unroll
                for (int j = 0; j < CAP2/64; ++j) {
                    float t = 0.f;
#pragma unroll
                    for (int k = 0; k < K_; ++k) t += e[j][k] * r[k];
                    cn[j] = (j * 64 + ln < Nc) ? 1.f / ((float)Nc * t) : 0.f;
                }
            }
#pragma unroll
            for (int j = 0; j < CAP2/64; ++j) {
                int n = j * 64 + ln;
                if (n >= Nc) continue;
                int idxn = idxList[c * CAP2 + n];
                int kb = 0; float best = e[j][0] * r[0];
#pragma unroll
                for (int k = 1; k < K_; ++k) {
                    float v = e[j][k] * r[k];
                    if (v > best) { best = v; kb = k; }
                }
                assign[idxn] = (float)(kb + c * K_);
                float scale = cn[j] * (float)Nc * (1.0f - GAMMA_) * invR[idxn];
#pragma unroll
                for (int k = 0; k < K_; ++k)
                    u.s.s_w[k][n] = e[j][k] * r[k] * scale;
            }
        }
        __syncthreads();

        // EMA: 256 threads, each owns d = tid, tid+256, tid+512
        float a0[K_] = {}, a1[K_] = {}, a2[K_] = {};
        int n = 0;
        for (; n + 1 < Nc; n += 2) {
            const float* rp0 = rawp + (size_t)u.s.s_idx[n] * D_;
            const float* rp1 = rawp + (size_t)u.s.s_idx[n + 1] * D_;
            float x0 = rp0[tid], x1 = rp0[tid + 256], x2 = rp0[tid + 512];
            float y0 = rp1[tid], y1 = rp1[tid + 256], y2 = rp1[tid + 512];
#pragma unroll
            for (int k = 0; k < K_; ++k) {
                float w0 = u.s.s_w[k][n], w1 = u.s.s_w[k][n + 1];
                a0[k] = fmaf(w0, x0, a0[k]); a0[k] = fmaf(w1, y0, a0[k]);
                a1[k] = fmaf(w0, x1, a1[k]); a1[k] = fmaf(w1, y1, a1[k]);
                a2[k] = fmaf(w0, x2, a2[k]); a2[k] = fmaf(w1, y2, a2[k]);
            }
        }
        if (n < Nc) {
            const float* rp0 = rawp + (size_t)u.s.s_idx[n] * D_;
            float x0 = rp0[tid], x1 = rp0[tid + 256], x2 = rp0[tid + 512];
#pragma unroll
            for (int k = 0; k < K_; ++k) {
                float w0 = u.s.s_w[k][n];
                a0[k] = fmaf(w0, x0, a0[k]);
                a1[k] = fmaf(w0, x1, a1[k]);
                a2[k] = fmaf(w0, x2, a2[k]);
            }
        }
#pragma unroll
        for (int k = 0; k < K_; ++k) {
            size_t o = protoOff + (size_t)k * D_;
            pnew[o + tid]       = fmaf(GAMMA_, proto[o + tid],       a0[k]);
            pnew[o + tid + 256] = fmaf(GAMMA_, proto[o + tid + 256], a1[k]);
            pnew[o + tid + 512] = fmaf(GAMMA_, proto[o + tid + 512], a2[k]);
        }
    }
}

extern "C" void kernel_launch(void* const* d_in, const int* in_sizes, int n_in,
                              void* d_out, int out_size, void* d_ws, size_t ws_size,
                              hipStream_t stream) {
    (void)in_sizes; (void)n_in; (void)out_size; (void)ws_size;
    const float* patch  = (const float*)d_in[0];
    const float* rawp   = (const float*)d_in[1];
    const float* proto  = (const float*)d_in[2];
    const float* saw    = (const float*)d_in[3];
    const int*   labels = (const int*)d_in[4];

    float* out    = (float*)d_out;
    float* logits = out;
    float* img    = out + 12606720;
    float* cls    = out + 12671040;
    float* assign = out + 12683840;
    float* pnew   = out + 12696384;

    // ws layout (16B-aligned sections):
    // [0,8)      bar (2 u32)        -- zeroed each launch
    // [32,1056)  cnt (256 i32)      -- zeroed each launch
    // [1056,...) invR, Abf, Bbf, idxList, EList, part
    unsigned* bar = (unsigned*)d_ws;
    int* cnt      = (int*)((char*)d_ws + 32);
    float* invR   = (float*)((char*)d_ws + 1056);              // N_ floats
    unsigned short* Abf = (unsigned short*)(invR + N_);        // N_*768 bf16
    unsigned short* Bbf = Abf + (size_t)N_ * D_;               // NPAD*768 bf16
    int*   idxList = (int*)(Bbf + (size_t)NPAD * D_);          // C_*CAP2
    float* EList   = (float*)(idxList + C_ * CAP2);            // C_*CAP2*EPAD
    float* part    = EList + (size_t)C_ * CAP2 * EPAD;         // MTILES*2*1024

    hipMemsetAsync(d_ws, 0, 1056, stream);   // reset barrier + cnt (graph-capturable)
    mega_kernel<<<NBLK, 256, 0, stream>>>(patch, rawp, proto, saw, labels,
                                          logits, img, cls, assign, pnew,
                                          bar, cnt, invR, Abf, Bbf,
                                          idxList, EList, part);
}

// Round 6
// 183.001 us; speedup vs baseline: 2.6537x; 2.6537x over previous
//
#include <hip/hip_runtime.h>
#include <math.h>

#define B_ 64
#define P_ 196
#define D_ 768
#define C_ 201
#define K_ 5
#define N_ (B_*P_)      // 12544
#define CK_ (C_*K_)     // 1005
#define NPAD 1024
#define NCLS 200
#define GAMMA_ 0.999f
#define INV_TEMP 5.0f
#define INV_EPS 20.0f
#define CAP2 256
#define EPAD 8          // padded floats per (c,slot) in EList
#define ROWS_TOT (2*N_ + NPAD)   // 26112 rows for the norm pass

typedef short s16x8 __attribute__((ext_vector_type(8)));
typedef float f32x4 __attribute__((ext_vector_type(4)));
typedef unsigned short u16x4 __attribute__((ext_vector_type(4)));

typedef __attribute__((address_space(3))) void lds_void;
typedef __attribute__((address_space(1))) const void g_void;
#define GLD16(gp, lp) __builtin_amdgcn_global_load_lds((g_void*)(gp), (lds_void*)(lp), 16, 0, 0)

__device__ __forceinline__ unsigned short f2bf(float f) {
    unsigned int u = __float_as_uint(f);
    unsigned int r = (u + 0x7FFFu + ((u >> 16) & 1u)) >> 16;
    return (unsigned short)r;
}

// ---------------- norms + pre-scaled bf16 conversion: ONE WAVE PER ROW ----------------
__global__ __launch_bounds__(256) void norm_all_kernel(
        const float* __restrict__ patch, const float* __restrict__ rawp,
        const float* __restrict__ proto, float* __restrict__ invR,
        unsigned short* __restrict__ Abf, unsigned short* __restrict__ Bbf,
        int* __restrict__ cnt) {
    if (blockIdx.x == 0 && threadIdx.x < C_) cnt[threadIdx.x] = 0;
    int gw = blockIdx.x * 4 + (threadIdx.x >> 6);   // row index
    int lane = threadIdx.x & 63;
    const float* src; unsigned short* dst; int realR; int r; bool wantInv = false;
    if (gw < N_) { r = gw; src = patch; dst = Abf; realR = N_; }
    else if (gw < 2 * N_) { r = gw - N_; src = rawp; dst = nullptr; realR = N_; wantInv = true; }
    else { r = gw - 2 * N_; src = proto; dst = Bbf; realR = CK_; }
    unsigned short* brow = dst ? dst + (size_t)r * D_ : nullptr;
    if (r >= realR) {  // zero-pad proto rows
        u16x4 z = (u16x4)0;
        *(u16x4*)(brow + lane * 4)       = z;
        *(u16x4*)(brow + lane * 4 + 256) = z;
        *(u16x4*)(brow + lane * 4 + 512) = z;
        return;
    }
    const float4* row4 = (const float4*)(src + (size_t)r * D_);
    float4 v0 = row4[lane], v1 = row4[lane + 64], v2 = row4[lane + 128];
    float s = v0.x*v0.x + v0.y*v0.y + v0.z*v0.z + v0.w*v0.w
            + v1.x*v1.x + v1.y*v1.y + v1.z*v1.z + v1.w*v1.w
            + v2.x*v2.x + v2.y*v2.y + v2.z*v2.z + v2.w*v2.w;
#pragma unroll
    for (int o = 1; o < 64; o <<= 1) s += __shfl_xor(s, o, 64);
    float sc = 1.f / fmaxf(sqrtf(s), 1e-12f);
    if (brow) {
        u16x4 p0 = { f2bf(v0.x*sc), f2bf(v0.y*sc), f2bf(v0.z*sc), f2bf(v0.w*sc) };
        u16x4 p1 = { f2bf(v1.x*sc), f2bf(v1.y*sc), f2bf(v1.z*sc), f2bf(v1.w*sc) };
        u16x4 p2 = { f2bf(v2.x*sc), f2bf(v2.y*sc), f2bf(v2.z*sc), f2bf(v2.w*sc) };
        *(u16x4*)(brow + lane * 4)       = p0;
        *(u16x4*)(brow + lane * 4 + 256) = p1;
        *(u16x4*)(brow + lane * 4 + 512) = p2;
    } else if (wantInv && lane == 0) invR[r] = sc;
}

// ---------------- 256x256 bf16 MFMA GEMM, BK=64, counted-vmcnt deep pipeline ----------------
// R10: structure change per regime-gate (T3/T4 at 256^2 is the proven big-gain quadrant).
//  - 8 waves (2M x 4N), per-wave 128x64 out, acc[8][4] f32x4 = 128 VGPR.
//  - 2-buffer LDS (128KB), stage tile t+2 AFTER tail barrier of iter t; head waits
//    vmcnt(8) (tile t done, t+1 stays in flight) - never drains mid-loop.
//  - both-sides XOR swizzle: LDS slot(row,ch) holds global chunk ch^(row&7); reads use
//    slot=(ks*4+q)^(mrow&7). 128B rows span all 32 banks (R7's 64B rows couldn't).
//  - setprio around MFMA clusters (T5).
#define BM2 256
#define BN2 256
#define BK2 64
#define KT (D_/BK2)     // 12
#define MT2 (N_/BM2)    // 49
__global__ __launch_bounds__(512, 2) void gemm_mfma_kernel(
    const unsigned short* __restrict__ Ab, const unsigned short* __restrict__ Bb,
    float* __restrict__ Cc,                 // logits [N_][CK_]
    float* __restrict__ part) {             // [MT2][3][1024] per-(tile,slot) col max
    __shared__ union {
        struct { short A[2][BM2 * BK2]; short B[2][BN2 * BK2]; } g;  // 131072 B
        float mw[2][3][BN2];                                          // epilogue reuse
    } u;
    int tid = threadIdx.x;                  // 0..511
    int wid = tid >> 6;
    int lane = tid & 63;
    int wr = wid >> 2, wc = wid & 3;        // 2M x 4N wave grid
    int mrow = lane & 15, q = lane >> 4;
    int slot0 = q ^ (mrow & 7);             // swizzled chunk for ks=0; ks=1 -> slot0^4

    // bijective XCD chunked swizzle for 196 blocks (196 = 8*24+4, m204 formula)
    int orig = blockIdx.x;
    int xcd = orig & 7, idx = orig >> 3;
    int wg = (xcd < 4 ? xcd * 25 : 100 + (xcd - 4) * 24) + idx;
    int mtile = wg >> 2, ntile = wg & 3;
    int mBase = mtile * BM2;
    int nBase = ntile * BN2;

    f32x4 acc[8][4];
#pragma unroll
    for (int i = 0; i < 8; ++i)
#pragma unroll
        for (int j = 0; j < 4; ++j) acc[i][j] = (f32x4)(0.f);

    // staging: thread covers chunks c = tid + 512*s (s=0..3) of A and of B.
    // chunk c -> (row=c>>3, ch=c&7); LDS dest linear at c*16B; global src pre-swizzled.
    const unsigned short* gA[4];
    const unsigned short* gB[4];
    int lof[4];
#pragma unroll
    for (int s = 0; s < 4; ++s) {
        int c = tid + 512 * s;
        int row = c >> 3, ch = c & 7;
        int chx = ch ^ (row & 7);
        gA[s] = Ab + (size_t)(mBase + row) * D_ + chx * 8;
        gB[s] = Bb + (size_t)(nBase + row) * D_ + chx * 8;
        lof[s] = c * 8;
    }
    auto stage = [&](int buf, int t) {
#pragma unroll
        for (int s = 0; s < 4; ++s) GLD16(gA[s] + t * BK2, &u.g.A[buf][lof[s]]);
#pragma unroll
        for (int s = 0; s < 4; ++s) GLD16(gB[s] + t * BK2, &u.g.B[buf][lof[s]]);
    };

    stage(0, 0);
    stage(1, 1);

    for (int t = 0; t < KT; ++t) {
        int cb = t & 1;
        if (t + 1 < KT) asm volatile("s_waitcnt vmcnt(8)" ::: "memory");
        else            asm volatile("s_waitcnt vmcnt(0)" ::: "memory");
        __builtin_amdgcn_s_barrier();
        __builtin_amdgcn_sched_barrier(0);
        const short* Ac = u.g.A[cb];
        const short* Bc = u.g.B[cb];
#pragma unroll
        for (int mh = 0; mh < 2; ++mh)
#pragma unroll
        for (int nh = 0; nh < 2; ++nh) {
            s16x8 a[4][2], b[2][2];
#pragma unroll
            for (int mf = 0; mf < 4; ++mf) {
                int row = wr * 128 + (mh * 4 + mf) * 16 + mrow;
                a[mf][0] = *(const s16x8*)&Ac[row * 64 + slot0 * 8];
                a[mf][1] = *(const s16x8*)&Ac[row * 64 + (slot0 ^ 4) * 8];
            }
#pragma unroll
            for (int nf = 0; nf < 2; ++nf) {
                int row = wc * 64 + (nh * 2 + nf) * 16 + mrow;
                b[nf][0] = *(const s16x8*)&Bc[row * 64 + slot0 * 8];
                b[nf][1] = *(const s16x8*)&Bc[row * 64 + (slot0 ^ 4) * 8];
            }
            __builtin_amdgcn_s_setprio(1);
#pragma unroll
            for (int mf = 0; mf < 4; ++mf)
#pragma unroll
            for (int nf = 0; nf < 2; ++nf) {
                acc[mh*4+mf][nh*2+nf] = __builtin_amdgcn_mfma_f32_16x16x32_bf16(
                    a[mf][0], b[nf][0], acc[mh*4+mf][nh*2+nf], 0, 0, 0);
                acc[mh*4+mf][nh*2+nf] = __builtin_amdgcn_mfma_f32_16x16x32_bf16(
                    a[mf][1], b[nf][1], acc[mh*4+mf][nh*2+nf], 0, 0, 0);
            }
            __builtin_amdgcn_s_setprio(0);
        }
        asm volatile("s_waitcnt lgkmcnt(0)" ::: "memory");
        __builtin_amdgcn_s_barrier();
        __builtin_amdgcn_sched_barrier(0);
        if (t + 2 < KT) stage(cb, t + 2);
    }

    // epilogue: C stores
#pragma unroll
    for (int m = 0; m < 8; ++m) {
        int gm = mBase + wr * 128 + m * 16 + q * 4;
#pragma unroll
        for (int j = 0; j < 4; ++j) {
            int gn = nBase + wc * 64 + j * 16 + mrow;
            if (gn < CK_) {
                Cc[(size_t)(gm + 0) * CK_ + gn] = acc[m][j][0];
                Cc[(size_t)(gm + 1) * CK_ + gn] = acc[m][j][1];
                Cc[(size_t)(gm + 2) * CK_ + gn] = acc[m][j][2];
                Cc[(size_t)(gm + 3) * CK_ + gn] = acc[m][j][3];
            }
        }
    }

    // fused per-image col max: 256-row tile spans up to 3 images (2 boundaries)
    int imgA = mBase / 196;
    int rs1 = 196 * (imgA + 1) - mBase;   // in (0,196]
    int rs2 = rs1 + 196;
#pragma unroll
    for (int j = 0; j < 4; ++j) {
        float m0 = -INFINITY, m1 = -INFINITY, m2 = -INFINITY;
#pragma unroll
        for (int m = 0; m < 8; ++m) {
            int lr = wr * 128 + m * 16 + q * 4;
#pragma unroll
            for (int r = 0; r < 4; ++r) {
                float v = acc[m][j][r];
                int row = lr + r;
                if (row >= rs2) m2 = fmaxf(m2, v);
                else if (row >= rs1) m1 = fmaxf(m1, v);
                else m0 = fmaxf(m0, v);
            }
        }
        m0 = fmaxf(m0, __shfl_xor(m0, 16)); m0 = fmaxf(m0, __shfl_xor(m0, 32));
        m1 = fmaxf(m1, __shfl_xor(m1, 16)); m1 = fmaxf(m1, __shfl_xor(m1, 32));
        m2 = fmaxf(m2, __shfl_xor(m2, 16)); m2 = fmaxf(m2, __shfl_xor(m2, 32));
        if (lane < 16) {
            int col = wc * 64 + j * 16 + lane;
            u.mw[wr][0][col] = m0;
            u.mw[wr][1][col] = m1;
            u.mw[wr][2][col] = m2;
        }
    }
    __syncthreads();
    if (tid < BN2) {
#pragma unroll
        for (int s = 0; s < 3; ++s) {
            float vmax = fmaxf(u.mw[0][s][tid], u.mw[1][s][tid]);
            part[(size_t)(mtile * 3 + s) * 1024 + nBase + tid] = vmax;
        }
    }
}

// ---------------- fused: imgcls (blocks [0,B_)) + compaction (blocks [B_,B_+49)) ----------------
__global__ __launch_bounds__(256) void post_kernel(
        const float* __restrict__ part, const float* __restrict__ saw,
        float* __restrict__ img, float* __restrict__ cls,
        const float* __restrict__ L, const int* __restrict__ labels,
        int* __restrict__ cnt, int* __restrict__ idxList, float* __restrict__ EList) {
    __shared__ float simg[CK_];
    if (blockIdx.x < B_) {
        int b = blockIdx.x;
        int t0 = (196 * b) >> 8;             // 256-row tiles now
        int t1 = (196 * b + 195) >> 8;
        for (int n = threadIdx.x; n < CK_; n += 256) {
            float m = -INFINITY;
            for (int t = t0; t <= t1; ++t) {
                int iA = (t << 8) / 196;
                int s = b - iA;              // 0..2 by construction
                m = fmaxf(m, part[(size_t)(t * 3 + s) * 1024 + n]);
            }
            img[b * CK_ + n] = m;
            simg[n] = m;
        }
        __syncthreads();
        int c = threadIdx.x;
        if (c < NCLS) {
            float w[K_];
            float mx = -INFINITY;
#pragma unroll
            for (int k = 0; k < K_; ++k) { w[k] = saw[c * K_ + k]; mx = fmaxf(mx, w[k]); }
            float ssum = 0.f;
#pragma unroll
            for (int k = 0; k < K_; ++k) { w[k] = expf(w[k] - mx); ssum += w[k]; }
            float acc = 0.f;
#pragma unroll
            for (int k = 0; k < K_; ++k)
                acc += simg[c * K_ + k] * (w[k] / ssum * (float)K_);
            cls[b * NCLS + c] = acc * INV_TEMP;
        }
    } else {
        int n = (blockIdx.x - B_) * 256 + threadIdx.x;
        if (n >= N_) return;
        int c = labels[n];
        int slot = atomicAdd(&cnt[c], 1);
        if (slot < CAP2) {
            idxList[c * CAP2 + slot] = n;
            const float* lp = L + (size_t)n * CK_ + c * K_;
            float e0 = expf(lp[0] * INV_EPS), e1 = expf(lp[1] * INV_EPS);
            float e2 = expf(lp[2] * INV_EPS), e3 = expf(lp[3] * INV_EPS);
            float e4 = expf(lp[4] * INV_EPS);
            float* ep = EList + ((size_t)c * CAP2 + slot) * EPAD;
            float4 v4 = { e0, e1, e2, e3 };
            *(float4*)ep = v4;
            ep[4] = e4;
        }
    }
}

// ---------------- fused sinkhorn + EMA: one block per class, 768 threads (12 waves) ----------------
#define NJ (CAP2/64)
__global__ __launch_bounds__(768) void sinkema_kernel(
    const int* __restrict__ cnt, const int* __restrict__ idxList,
    const float* __restrict__ EList, const float* __restrict__ invR,
    const float* __restrict__ rawP, const float* __restrict__ proto,
    float* __restrict__ outAssign, float* __restrict__ outProto) {
    int c = blockIdx.x;
    int tid = threadIdx.x;
    int Nc = cnt[c]; if (Nc > CAP2) Nc = CAP2;
    size_t protoOff = (size_t)c * K_ * D_;
    if (Nc == 0) {  // absent class: copy prototypes through
        for (int i = tid; i < K_ * D_; i += 768)
            outProto[protoOff + i] = proto[protoOff + i];
        return;
    }
    __shared__ float s_w[K_][CAP2];
    __shared__ int s_idx[CAP2];
    for (int i = tid; i < CAP2; i += 768)
        s_idx[i] = (i < Nc) ? idxList[c * CAP2 + i] : 0;
    __syncthreads();   // R10: s_idx visible before wave0 uses it (fixes latent race)

    if (tid < 64) {   // wave 0: sinkhorn for this class
        int lane = tid;
        float e[NJ][K_];
        float cn[NJ];
#pragma unroll
        for (int j = 0; j < NJ; ++j) {
            int n = j * 64 + lane;
            bool v = n < Nc;
            cn[j] = v ? 1.f : 0.f;
            const float* ep = EList + ((size_t)c * CAP2 + n) * EPAD;
            float4 v4 = v ? *(const float4*)ep : make_float4(0.f, 0.f, 0.f, 0.f);
            e[j][0] = v4.x; e[j][1] = v4.y; e[j][2] = v4.z; e[j][3] = v4.w;
            e[j][4] = v ? ep[4] : 0.f;
        }
        float r[K_];
        for (int it = 0; it < 3; ++it) {
#pragma unroll
            for (int k = 0; k < K_; ++k) {
                float s = 0.f;
#pragma unroll
                for (int j = 0; j < NJ; ++j) s += e[j][k] * cn[j];
                for (int o = 32; o > 0; o >>= 1) s += __shfl_xor(s, o, 64);
                r[k] = 1.f / ((float)K_ * s);
            }
#pragma unroll
            for (int j = 0; j < NJ; ++j) {
                float t = 0.f;
#pragma unroll
                for (int k = 0; k < K_; ++k) t += e[j][k] * r[k];
                cn[j] = (j * 64 + lane < Nc) ? 1.f / ((float)Nc * t) : 0.f;
            }
        }
#pragma unroll
        for (int j = 0; j < NJ; ++j) {
            int n = j * 64 + lane;
            if (n >= Nc) continue;
            int idxn = s_idx[n];
            int kb = 0; float best = e[j][0] * r[0];
#pragma unroll
            for (int k = 1; k < K_; ++k) {
                float v = e[j][k] * r[k];
                if (v > best) { best = v; kb = k; }
            }
            outAssign[idxn] = (float)(kb + c * K_);
            float scale = cn[j] * (float)Nc * (1.0f - GAMMA_) * invR[idxn];
#pragma unroll
            for (int k = 0; k < K_; ++k)
                s_w[k][n] = e[j][k] * r[k] * scale;
        }
    }
    __syncthreads();

    // EMA: 768 threads, thread owns d = tid; unroll-4 keeps 4 gathered rows in flight
    float acc[K_] = {};
    int n = 0;
    for (; n + 3 < Nc; n += 4) {
        float v0 = rawP[(size_t)s_idx[n]     * D_ + tid];
        float v1 = rawP[(size_t)s_idx[n + 1] * D_ + tid];
        float v2 = rawP[(size_t)s_idx[n + 2] * D_ + tid];
        float v3 = rawP[(size_t)s_idx[n + 3] * D_ + tid];
#pragma unroll
        for (int k = 0; k < K_; ++k) {
            acc[k] = fmaf(s_w[k][n],     v0, acc[k]);
            acc[k] = fmaf(s_w[k][n + 1], v1, acc[k]);
            acc[k] = fmaf(s_w[k][n + 2], v2, acc[k]);
            acc[k] = fmaf(s_w[k][n + 3], v3, acc[k]);
        }
    }
    for (; n < Nc; ++n) {
        float v0 = rawP[(size_t)s_idx[n] * D_ + tid];
#pragma unroll
        for (int k = 0; k < K_; ++k) acc[k] = fmaf(s_w[k][n], v0, acc[k]);
    }
#pragma unroll
    for (int k = 0; k < K_; ++k) {
        size_t o = protoOff + (size_t)k * D_ + tid;
        outProto[o] = fmaf(GAMMA_, proto[o], acc[k]);
    }
}

extern "C" void kernel_launch(void* const* d_in, const int* in_sizes, int n_in,
                              void* d_out, int out_size, void* d_ws, size_t ws_size,
                              hipStream_t stream) {
    (void)in_sizes; (void)n_in; (void)out_size; (void)ws_size;
    const float* patch  = (const float*)d_in[0];
    const float* rawp   = (const float*)d_in[1];
    const float* proto  = (const float*)d_in[2];
    const float* saw    = (const float*)d_in[3];
    const int*   labels = (const int*)d_in[4];

    float* out    = (float*)d_out;
    float* logits = out;
    float* img    = out + 12606720;
    float* cls    = out + 12671040;
    float* assign = out + 12683840;
    float* pnew   = out + 12696384;

    float* ws   = (float*)d_ws;
    float* invR = ws;                                      // N_
    unsigned short* Abf = (unsigned short*)(ws + N_);      // N_*768 bf16 (pre-normalized)
    unsigned short* Bbf = Abf + (size_t)N_ * D_;           // NPAD*768 bf16 (pre-normalized)
    int*   cnt     = (int*)(Bbf + (size_t)NPAD * D_);      // 256
    int*   idxList = cnt + 256;                            // C_*CAP2
    float* EList   = (float*)(idxList + C_ * CAP2);        // C_*CAP2*EPAD
    float* part    = EList + (size_t)2 * C_ * K_ * CAP2;   // MT2*3*1024

    norm_all_kernel<<<ROWS_TOT / 4, 256, 0, stream>>>(patch, rawp, proto, invR, Abf, Bbf, cnt);
    gemm_mfma_kernel<<<MT2 * 4, 512, 0, stream>>>(Abf, Bbf, logits, part);
    post_kernel<<<B_ + N_ / 256, 256, 0, stream>>>(part, saw, img, cls, logits, labels,
                                                   cnt, idxList, EList);
    sinkema_kernel<<<C_, 768, 0, stream>>>(cnt, idxList, EList, invR, rawp, proto,
                                           assign, pnew);
}

// Round 7
// 179.903 us; speedup vs baseline: 2.6994x; 1.0172x over previous
//
#include <hip/hip_runtime.h>
#include <math.h>

#define B_ 64
#define P_ 196
#define D_ 768
#define C_ 201
#define K_ 5
#define N_ (B_*P_)      // 12544
#define CK_ (C_*K_)     // 1005
#define NPAD 1024
#define NCLS 200
#define GAMMA_ 0.999f
#define INV_TEMP 5.0f
#define INV_EPS 20.0f
#define CAP2 256
#define EPAD 8          // padded floats per (c,slot) in EList
#define ROWS_TOT (2*N_ + NPAD)   // 26112 rows for the norm pass

typedef short s16x8 __attribute__((ext_vector_type(8)));
typedef float f32x4 __attribute__((ext_vector_type(4)));
typedef unsigned short u16x4 __attribute__((ext_vector_type(4)));

typedef __attribute__((address_space(3))) void lds_void;
typedef __attribute__((address_space(1))) const void g_void;
#define GLD16(gp, lp) __builtin_amdgcn_global_load_lds((g_void*)(gp), (lds_void*)(lp), 16, 0, 0)

__device__ __forceinline__ unsigned short f2bf(float f) {
    unsigned int u = __float_as_uint(f);
    unsigned int r = (u + 0x7FFFu + ((u >> 16) & 1u)) >> 16;
    return (unsigned short)r;
}

// ---------------- norms + pre-scaled bf16 conversion: ONE WAVE PER ROW ----------------
__global__ __launch_bounds__(256) void norm_all_kernel(
        const float* __restrict__ patch, const float* __restrict__ rawp,
        const float* __restrict__ proto, float* __restrict__ invR,
        unsigned short* __restrict__ Abf, unsigned short* __restrict__ Bbf,
        int* __restrict__ cnt) {
    if (blockIdx.x == 0 && threadIdx.x < C_) cnt[threadIdx.x] = 0;
    int gw = blockIdx.x * 4 + (threadIdx.x >> 6);   // row index
    int lane = threadIdx.x & 63;
    const float* src; unsigned short* dst; int realR; int r; bool wantInv = false;
    if (gw < N_) { r = gw; src = patch; dst = Abf; realR = N_; }
    else if (gw < 2 * N_) { r = gw - N_; src = rawp; dst = nullptr; realR = N_; wantInv = true; }
    else { r = gw - 2 * N_; src = proto; dst = Bbf; realR = CK_; }
    unsigned short* brow = dst ? dst + (size_t)r * D_ : nullptr;
    if (r >= realR) {  // zero-pad proto rows
        u16x4 z = (u16x4)0;
        *(u16x4*)(brow + lane * 4)       = z;
        *(u16x4*)(brow + lane * 4 + 256) = z;
        *(u16x4*)(brow + lane * 4 + 512) = z;
        return;
    }
    const float4* row4 = (const float4*)(src + (size_t)r * D_);
    float4 v0 = row4[lane], v1 = row4[lane + 64], v2 = row4[lane + 128];
    float s = v0.x*v0.x + v0.y*v0.y + v0.z*v0.z + v0.w*v0.w
            + v1.x*v1.x + v1.y*v1.y + v1.z*v1.z + v1.w*v1.w
            + v2.x*v2.x + v2.y*v2.y + v2.z*v2.z + v2.w*v2.w;
#pragma unroll
    for (int o = 1; o < 64; o <<= 1) s += __shfl_xor(s, o, 64);
    float sc = 1.f / fmaxf(sqrtf(s), 1e-12f);
    if (brow) {
        u16x4 p0 = { f2bf(v0.x*sc), f2bf(v0.y*sc), f2bf(v0.z*sc), f2bf(v0.w*sc) };
        u16x4 p1 = { f2bf(v1.x*sc), f2bf(v1.y*sc), f2bf(v1.z*sc), f2bf(v1.w*sc) };
        u16x4 p2 = { f2bf(v2.x*sc), f2bf(v2.y*sc), f2bf(v2.z*sc), f2bf(v2.w*sc) };
        *(u16x4*)(brow + lane * 4)       = p0;
        *(u16x4*)(brow + lane * 4 + 256) = p1;
        *(u16x4*)(brow + lane * 4 + 512) = p2;
    } else if (wantInv && lane == 0) invR[r] = sc;
}

// ---------------- 256x256 bf16 MFMA GEMM, BK=64, counted-vmcnt deep pipeline ----------------
// R11: fragment hoisting (24 ds_read_b128/wave/K-tile, was 48 -- A was read twice) and
//   split-MFMA schedule: reads -> 32 MFMA (nf0-1) -> lgkm(0)+barrier -> stage(t+2) ->
//   32 MFMA (nf2-3). Stage issue hidden under MFMA; vmcnt never drained mid-loop.
//   Swizzles unchanged from R10 (bank-conflict 0 verified; FETCH 16MB verified).
#define BM2 256
#define BN2 256
#define BK2 64
#define KT (D_/BK2)     // 12
#define MT2 (N_/BM2)    // 49
__global__ __launch_bounds__(512, 2) void gemm_mfma_kernel(
    const unsigned short* __restrict__ Ab, const unsigned short* __restrict__ Bb,
    float* __restrict__ Cc,                 // logits [N_][CK_]
    float* __restrict__ part) {             // [MT2][3][1024] per-(tile,slot) col max
    __shared__ union {
        struct { short A[2][BM2 * BK2]; short B[2][BN2 * BK2]; } g;  // 131072 B
        float mw[2][3][BN2];                                          // epilogue reuse
    } u;
    int tid = threadIdx.x;                  // 0..511
    int wid = tid >> 6;
    int lane = tid & 63;
    int wr = wid >> 2, wc = wid & 3;        // 2M x 4N wave grid
    int mrow = lane & 15, q = lane >> 4;
    int slot0 = q ^ (mrow & 7);             // swizzled chunk for ks=0; ks=1 -> slot0^4

    // bijective XCD chunked swizzle for 196 blocks (196 = 8*24+4, m204 formula)
    int orig = blockIdx.x;
    int xcd = orig & 7, idx = orig >> 3;
    int wg = (xcd < 4 ? xcd * 25 : 100 + (xcd - 4) * 24) + idx;
    int mtile = wg >> 2, ntile = wg & 3;
    int mBase = mtile * BM2;
    int nBase = ntile * BN2;

    f32x4 acc[8][4];
#pragma unroll
    for (int i = 0; i < 8; ++i)
#pragma unroll
        for (int j = 0; j < 4; ++j) acc[i][j] = (f32x4)(0.f);

    // staging: thread covers chunks c = tid + 512*s (s=0..3) of A and of B.
    // chunk c -> (row=c>>3, ch=c&7); LDS dest linear at c*16B; global src pre-swizzled.
    const unsigned short* gA[4];
    const unsigned short* gB[4];
    int lof[4];
#pragma unroll
    for (int s = 0; s < 4; ++s) {
        int c = tid + 512 * s;
        int row = c >> 3, ch = c & 7;
        int chx = ch ^ (row & 7);
        gA[s] = Ab + (size_t)(mBase + row) * D_ + chx * 8;
        gB[s] = Bb + (size_t)(nBase + row) * D_ + chx * 8;
        lof[s] = c * 8;
    }
    auto stage = [&](int buf, int t) {
#pragma unroll
        for (int s = 0; s < 4; ++s) GLD16(gA[s] + t * BK2, &u.g.A[buf][lof[s]]);
#pragma unroll
        for (int s = 0; s < 4; ++s) GLD16(gB[s] + t * BK2, &u.g.B[buf][lof[s]]);
    };

    stage(0, 0);
    stage(1, 1);

    for (int t = 0; t < KT; ++t) {
        int cb = t & 1;
        if (t + 1 < KT) asm volatile("s_waitcnt vmcnt(8)" ::: "memory");
        else            asm volatile("s_waitcnt vmcnt(0)" ::: "memory");
        __builtin_amdgcn_s_barrier();
        __builtin_amdgcn_sched_barrier(0);
        const short* Ac = u.g.A[cb];
        const short* Bc = u.g.B[cb];
        // hoisted fragment loads: a (16 reads) + b01 (4 reads)
        s16x8 a[8][2], b01[2][2], b23[2][2];
#pragma unroll
        for (int mf = 0; mf < 8; ++mf) {
            int row = wr * 128 + mf * 16 + mrow;
            a[mf][0] = *(const s16x8*)&Ac[row * 64 + slot0 * 8];
            a[mf][1] = *(const s16x8*)&Ac[row * 64 + (slot0 ^ 4) * 8];
        }
#pragma unroll
        for (int nf = 0; nf < 2; ++nf) {
            int row = wc * 64 + nf * 16 + mrow;
            b01[nf][0] = *(const s16x8*)&Bc[row * 64 + slot0 * 8];
            b01[nf][1] = *(const s16x8*)&Bc[row * 64 + (slot0 ^ 4) * 8];
        }
        // issue b23 reads too (before the stage barrier -- same buffer, must precede it)
#pragma unroll
        for (int nf = 0; nf < 2; ++nf) {
            int row = wc * 64 + (nf + 2) * 16 + mrow;
            b23[nf][0] = *(const s16x8*)&Bc[row * 64 + slot0 * 8];
            b23[nf][1] = *(const s16x8*)&Bc[row * 64 + (slot0 ^ 4) * 8];
        }
        // first half: nf 0-1 (compiler inserts counted lgkmcnt; reads overlap MFMAs)
        __builtin_amdgcn_s_setprio(1);
#pragma unroll
        for (int mf = 0; mf < 8; ++mf)
#pragma unroll
            for (int nf = 0; nf < 2; ++nf) {
                acc[mf][nf] = __builtin_amdgcn_mfma_f32_16x16x32_bf16(
                    a[mf][0], b01[nf][0], acc[mf][nf], 0, 0, 0);
                acc[mf][nf] = __builtin_amdgcn_mfma_f32_16x16x32_bf16(
                    a[mf][1], b01[nf][1], acc[mf][nf], 0, 0, 0);
            }
        __builtin_amdgcn_s_setprio(0);
        // all reads of this buffer done -> safe to overwrite with tile t+2
        asm volatile("s_waitcnt lgkmcnt(0)" ::: "memory");
        __builtin_amdgcn_s_barrier();
        __builtin_amdgcn_sched_barrier(0);
        if (t + 2 < KT) stage(cb, t + 2);
        // second half: nf 2-3 hides the stage issue
        __builtin_amdgcn_s_setprio(1);
#pragma unroll
        for (int mf = 0; mf < 8; ++mf)
#pragma unroll
            for (int nf = 0; nf < 2; ++nf) {
                acc[mf][nf + 2] = __builtin_amdgcn_mfma_f32_16x16x32_bf16(
                    a[mf][0], b23[nf][0], acc[mf][nf + 2], 0, 0, 0);
                acc[mf][nf + 2] = __builtin_amdgcn_mfma_f32_16x16x32_bf16(
                    a[mf][1], b23[nf][1], acc[mf][nf + 2], 0, 0, 0);
            }
        __builtin_amdgcn_s_setprio(0);
    }

    // epilogue: C stores
#pragma unroll
    for (int m = 0; m < 8; ++m) {
        int gm = mBase + wr * 128 + m * 16 + q * 4;
#pragma unroll
        for (int j = 0; j < 4; ++j) {
            int gn = nBase + wc * 64 + j * 16 + mrow;
            if (gn < CK_) {
                Cc[(size_t)(gm + 0) * CK_ + gn] = acc[m][j][0];
                Cc[(size_t)(gm + 1) * CK_ + gn] = acc[m][j][1];
                Cc[(size_t)(gm + 2) * CK_ + gn] = acc[m][j][2];
                Cc[(size_t)(gm + 3) * CK_ + gn] = acc[m][j][3];
            }
        }
    }

    // fused per-image col max: 256-row tile spans up to 3 images (2 boundaries)
    int imgA = mBase / 196;
    int rs1 = 196 * (imgA + 1) - mBase;   // in (0,196]
    int rs2 = rs1 + 196;
#pragma unroll
    for (int j = 0; j < 4; ++j) {
        float m0 = -INFINITY, m1 = -INFINITY, m2 = -INFINITY;
#pragma unroll
        for (int m = 0; m < 8; ++m) {
            int lr = wr * 128 + m * 16 + q * 4;
#pragma unroll
            for (int r = 0; r < 4; ++r) {
                float v = acc[m][j][r];
                int row = lr + r;
                if (row >= rs2) m2 = fmaxf(m2, v);
                else if (row >= rs1) m1 = fmaxf(m1, v);
                else m0 = fmaxf(m0, v);
            }
        }
        m0 = fmaxf(m0, __shfl_xor(m0, 16)); m0 = fmaxf(m0, __shfl_xor(m0, 32));
        m1 = fmaxf(m1, __shfl_xor(m1, 16)); m1 = fmaxf(m1, __shfl_xor(m1, 32));
        m2 = fmaxf(m2, __shfl_xor(m2, 16)); m2 = fmaxf(m2, __shfl_xor(m2, 32));
        if (lane < 16) {
            int col = wc * 64 + j * 16 + lane;
            u.mw[wr][0][col] = m0;
            u.mw[wr][1][col] = m1;
            u.mw[wr][2][col] = m2;
        }
    }
    __syncthreads();
    if (tid < BN2) {
#pragma unroll
        for (int s = 0; s < 3; ++s) {
            float vmax = fmaxf(u.mw[0][s][tid], u.mw[1][s][tid]);
            part[(size_t)(mtile * 3 + s) * 1024 + nBase + tid] = vmax;
        }
    }
}

// ---------------- fused: imgcls (blocks [0,B_)) + compaction (blocks [B_,B_+49)) ----------------
__global__ __launch_bounds__(256) void post_kernel(
        const float* __restrict__ part, const float* __restrict__ saw,
        float* __restrict__ img, float* __restrict__ cls,
        const float* __restrict__ L, const int* __restrict__ labels,
        int* __restrict__ cnt, int* __restrict__ idxList, float* __restrict__ EList) {
    __shared__ float simg[CK_];
    if (blockIdx.x < B_) {
        int b = blockIdx.x;
        int t0 = (196 * b) >> 8;             // 256-row tiles
        int t1 = (196 * b + 195) >> 8;
        for (int n = threadIdx.x; n < CK_; n += 256) {
            float m = -INFINITY;
            for (int t = t0; t <= t1; ++t) {
                int iA = (t << 8) / 196;
                int s = b - iA;              // 0..2 by construction
                m = fmaxf(m, part[(size_t)(t * 3 + s) * 1024 + n]);
            }
            img[b * CK_ + n] = m;
            simg[n] = m;
        }
        __syncthreads();
        int c = threadIdx.x;
        if (c < NCLS) {
            float w[K_];
            float mx = -INFINITY;
#pragma unroll
            for (int k = 0; k < K_; ++k) { w[k] = saw[c * K_ + k]; mx = fmaxf(mx, w[k]); }
            float ssum = 0.f;
#pragma unroll
            for (int k = 0; k < K_; ++k) { w[k] = expf(w[k] - mx); ssum += w[k]; }
            float acc = 0.f;
#pragma unroll
            for (int k = 0; k < K_; ++k)
                acc += simg[c * K_ + k] * (w[k] / ssum * (float)K_);
            cls[b * NCLS + c] = acc * INV_TEMP;
        }
    } else {
        int n = (blockIdx.x - B_) * 256 + threadIdx.x;
        if (n >= N_) return;
        int c = labels[n];
        int slot = atomicAdd(&cnt[c], 1);
        if (slot < CAP2) {
            idxList[c * CAP2 + slot] = n;
            const float* lp = L + (size_t)n * CK_ + c * K_;
            float e0 = expf(lp[0] * INV_EPS), e1 = expf(lp[1] * INV_EPS);
            float e2 = expf(lp[2] * INV_EPS), e3 = expf(lp[3] * INV_EPS);
            float e4 = expf(lp[4] * INV_EPS);
            float* ep = EList + ((size_t)c * CAP2 + slot) * EPAD;
            float4 v4 = { e0, e1, e2, e3 };
            *(float4*)ep = v4;
            ep[4] = e4;
        }
    }
}

// ---------------- fused sinkhorn + EMA: one block per class, 768 threads (12 waves) ----------------
#define NJ (CAP2/64)
__global__ __launch_bounds__(768) void sinkema_kernel(
    const int* __restrict__ cnt, const int* __restrict__ idxList,
    const float* __restrict__ EList, const float* __restrict__ invR,
    const float* __restrict__ rawP, const float* __restrict__ proto,
    float* __restrict__ outAssign, float* __restrict__ outProto) {
    int c = blockIdx.x;
    int tid = threadIdx.x;
    int Nc = cnt[c]; if (Nc > CAP2) Nc = CAP2;
    size_t protoOff = (size_t)c * K_ * D_;
    if (Nc == 0) {  // absent class: copy prototypes through
        for (int i = tid; i < K_ * D_; i += 768)
            outProto[protoOff + i] = proto[protoOff + i];
        return;
    }
    __shared__ float s_w[K_][CAP2];
    __shared__ int s_idx[CAP2];
    for (int i = tid; i < CAP2; i += 768)
        s_idx[i] = (i < Nc) ? idxList[c * CAP2 + i] : 0;
    __syncthreads();   // s_idx visible before wave0 uses it

    if (tid < 64) {   // wave 0: sinkhorn for this class
        int lane = tid;
        float e[NJ][K_];
        float cn[NJ];
#pragma unroll
        for (int j = 0; j < NJ; ++j) {
            int n = j * 64 + lane;
            bool v = n < Nc;
            cn[j] = v ? 1.f : 0.f;
            const float* ep = EList + ((size_t)c * CAP2 + n) * EPAD;
            float4 v4 = v ? *(const float4*)ep : make_float4(0.f, 0.f, 0.f, 0.f);
            e[j][0] = v4.x; e[j][1] = v4.y; e[j][2] = v4.z; e[j][3] = v4.w;
            e[j][4] = v ? ep[4] : 0.f;
        }
        float r[K_];
        for (int it = 0; it < 3; ++it) {
#pragma unroll
            for (int k = 0; k < K_; ++k) {
                float s = 0.f;
#pragma unroll
                for (int j = 0; j < NJ; ++j) s += e[j][k] * cn[j];
                for (int o = 32; o > 0; o >>= 1) s += __shfl_xor(s, o, 64);
                r[k] = 1.f / ((float)K_ * s);
            }
#pragma unroll
            for (int j = 0; j < NJ; ++j) {
                float t = 0.f;
#pragma unroll
                for (int k = 0; k < K_; ++k) t += e[j][k] * r[k];
                cn[j] = (j * 64 + lane < Nc) ? 1.f / ((float)Nc * t) : 0.f;
            }
        }
#pragma unroll
        for (int j = 0; j < NJ; ++j) {
            int n = j * 64 + lane;
            if (n >= Nc) continue;
            int idxn = s_idx[n];
            int kb = 0; float best = e[j][0] * r[0];
#pragma unroll
            for (int k = 1; k < K_; ++k) {
                float v = e[j][k] * r[k];
                if (v > best) { best = v; kb = k; }
            }
            outAssign[idxn] = (float)(kb + c * K_);
            float scale = cn[j] * (float)Nc * (1.0f - GAMMA_) * invR[idxn];
#pragma unroll
            for (int k = 0; k < K_; ++k)
                s_w[k][n] = e[j][k] * r[k] * scale;
        }
    }
    __syncthreads();

    // EMA: 768 threads, thread owns d = tid; unroll-4 keeps 4 gathered rows in flight
    float acc[K_] = {};
    int n = 0;
    for (; n + 3 < Nc; n += 4) {
        float v0 = rawP[(size_t)s_idx[n]     * D_ + tid];
        float v1 = rawP[(size_t)s_idx[n + 1] * D_ + tid];
        float v2 = rawP[(size_t)s_idx[n + 2] * D_ + tid];
        float v3 = rawP[(size_t)s_idx[n + 3] * D_ + tid];
#pragma unroll
        for (int k = 0; k < K_; ++k) {
            acc[k] = fmaf(s_w[k][n],     v0, acc[k]);
            acc[k] = fmaf(s_w[k][n + 1], v1, acc[k]);
            acc[k] = fmaf(s_w[k][n + 2], v2, acc[k]);
            acc[k] = fmaf(s_w[k][n + 3], v3, acc[k]);
        }
    }
    for (; n < Nc; ++n) {
        float v0 = rawP[(size_t)s_idx[n] * D_ + tid];
#pragma unroll
        for (int k = 0; k < K_; ++k) acc[k] = fmaf(s_w[k][n], v0, acc[k]);
    }
#pragma unroll
    for (int k = 0; k < K_; ++k) {
        size_t o = protoOff + (size_t)k * D_ + tid;
        outProto[o] = fmaf(GAMMA_, proto[o], acc[k]);
    }
}

extern "C" void kernel_launch(void* const* d_in, const int* in_sizes, int n_in,
                              void* d_out, int out_size, void* d_ws, size_t ws_size,
                              hipStream_t stream) {
    (void)in_sizes; (void)n_in; (void)out_size; (void)ws_size;
    const float* patch  = (const float*)d_in[0];
    const float* rawp   = (const float*)d_in[1];
    const float* proto  = (const float*)d_in[2];
    const float* saw    = (const float*)d_in[3];
    const int*   labels = (const int*)d_in[4];

    float* out    = (float*)d_out;
    float* logits = out;
    float* img    = out + 12606720;
    float* cls    = out + 12671040;
    float* assign = out + 12683840;
    float* pnew   = out + 12696384;

    float* ws   = (float*)d_ws;
    float* invR = ws;                                      // N_
    unsigned short* Abf = (unsigned short*)(ws + N_);      // N_*768 bf16 (pre-normalized)
    unsigned short* Bbf = Abf + (size_t)N_ * D_;           // NPAD*768 bf16 (pre-normalized)
    int*   cnt     = (int*)(Bbf + (size_t)NPAD * D_);      // 256
    int*   idxList = cnt + 256;                            // C_*CAP2
    float* EList   = (float*)(idxList + C_ * CAP2);        // C_*CAP2*EPAD
    float* part    = EList + (size_t)2 * C_ * K_ * CAP2;   // MT2*3*1024

    norm_all_kernel<<<ROWS_TOT / 4, 256, 0, stream>>>(patch, rawp, proto, invR, Abf, Bbf, cnt);
    gemm_mfma_kernel<<<MT2 * 4, 512, 0, stream>>>(Abf, Bbf, logits, part);
    post_kernel<<<B_ + N_ / 256, 256, 0, stream>>>(part, saw, img, cls, logits, labels,
                                                   cnt, idxList, EList);
    sinkema_kernel<<<C_, 768, 0, stream>>>(cnt, idxList, EList, invR, rawp, proto,
                                           assign, pnew);
}